// Round 2
// baseline (3161.119 us; speedup 1.0000x reference)
//
#include <hip/hip_runtime.h>
#include <math.h>

// SimpleGNN forward on MI355X.
// NOTE: harness materializes integer inputs as int32 -> edge_index is const int*.
// Stages:
//   init   : deg=1 (self loop), zero acc1
//   degree : deg[col] += 1 per edge (float atomics)
//   dinv   : deg <- rsqrt(deg)
//   gemm1  : h1lin = x @ W1                    [N,16]
//   agg1   : acc1[col] += h1lin[row]*norm      (16 float atomics/edge)
//   relu2  : h = relu(acc1 + h1lin*dinv^2 + b1); h2 = h @ W2;
//            node_out = h2*dinv^2 + b2         (self-loop term + bias init)
//   edge   : edge_out = MLP(h[row],h[col]);  node_out[col] += h2[row]*norm (atomics)
//
// Workspace (floats): deg[N] | h1lin[16N] | acc1[16N] | h[16N] | h2[2N]
//   total 51N floats = 20.4 MB for N=100000.

#define TPB 256

__global__ __launch_bounds__(TPB) void init_kernel(float* __restrict__ deg,
                                                   float* __restrict__ acc1, int N) {
    int i = blockIdx.x * TPB + threadIdx.x;
    if (i >= N) return;
    deg[i] = 1.0f;  // self loop
    float4 z = {0.f, 0.f, 0.f, 0.f};
    float4* a1 = (float4*)(acc1 + (size_t)i * 16);
    a1[0] = z; a1[1] = z; a1[2] = z; a1[3] = z;
}

__global__ __launch_bounds__(TPB) void degree_kernel(const int* __restrict__ col,
                                                     float* __restrict__ deg, int E) {
    int e = blockIdx.x * TPB + threadIdx.x;
    if (e >= E) return;
    atomicAdd(&deg[col[e]], 1.0f);
}

__global__ __launch_bounds__(TPB) void dinv_kernel(float* __restrict__ deg, int N) {
    int i = blockIdx.x * TPB + threadIdx.x;
    if (i >= N) return;
    deg[i] = rsqrtf(deg[i]);  // deg >= 1 always (self loop)
}

// x [N,128] @ W1 [128,16] -> h1lin [N,16].  64 rows per block, 256 threads.
// LDS x tile padded to stride 132 floats: distinct rows -> distinct banks.
__global__ __launch_bounds__(TPB) void gemm1_kernel(const float* __restrict__ x,
                                                    const float* __restrict__ W1,
                                                    float* __restrict__ h1lin, int N) {
    __shared__ float xs[64][132];
    __shared__ float w1s[128 * 16];
    int r0 = blockIdx.x * 64;
    int t  = threadIdx.x;

    // W1: 2048 floats = 512 float4
    for (int l = t; l < 512; l += TPB)
        ((float4*)w1s)[l] = ((const float4*)W1)[l];
    // x tile: 64 rows x 32 float4
    for (int l = t; l < 2048; l += TPB) {
        int r = l >> 5, q = l & 31;
        float4 v = {0.f, 0.f, 0.f, 0.f};
        if (r0 + r < N) v = ((const float4*)(x + (size_t)(r0 + r) * 128))[q];
        *(float4*)&xs[r][q * 4] = v;
    }
    __syncthreads();

    int row = t >> 2, kq = t & 3;  // 4 threads per row, 4 outputs each
    float4 a = {0.f, 0.f, 0.f, 0.f};
    #pragma unroll
    for (int j4 = 0; j4 < 32; ++j4) {
        float4 xv = *(const float4*)&xs[row][j4 * 4];
        const float* wp = &w1s[(j4 * 4) * 16 + kq * 4];
        float4 w0 = *(const float4*)(wp +  0);
        float4 w1 = *(const float4*)(wp + 16);
        float4 w2 = *(const float4*)(wp + 32);
        float4 w3 = *(const float4*)(wp + 48);
        a.x = fmaf(xv.x, w0.x, a.x); a.y = fmaf(xv.x, w0.y, a.y);
        a.z = fmaf(xv.x, w0.z, a.z); a.w = fmaf(xv.x, w0.w, a.w);
        a.x = fmaf(xv.y, w1.x, a.x); a.y = fmaf(xv.y, w1.y, a.y);
        a.z = fmaf(xv.y, w1.z, a.z); a.w = fmaf(xv.y, w1.w, a.w);
        a.x = fmaf(xv.z, w2.x, a.x); a.y = fmaf(xv.z, w2.y, a.y);
        a.z = fmaf(xv.z, w2.z, a.z); a.w = fmaf(xv.z, w2.w, a.w);
        a.x = fmaf(xv.w, w3.x, a.x); a.y = fmaf(xv.w, w3.y, a.y);
        a.z = fmaf(xv.w, w3.z, a.z); a.w = fmaf(xv.w, w3.w, a.w);
    }
    if (r0 + row < N)
        *(float4*)(h1lin + (size_t)(r0 + row) * 16 + kq * 4) = a;
}

__global__ __launch_bounds__(TPB) void agg1_kernel(const int* __restrict__ ei,
                                                   const float* __restrict__ dinv,
                                                   const float* __restrict__ h1lin,
                                                   float* __restrict__ acc1, int E) {
    int e = blockIdx.x * TPB + threadIdx.x;
    if (e >= E) return;
    int r = ei[e], c = ei[(size_t)E + e];
    float nrm = dinv[r] * dinv[c];
    const float4* hr = (const float4*)(h1lin + (size_t)r * 16);
    float* ac = acc1 + (size_t)c * 16;
    #pragma unroll
    for (int q = 0; q < 4; ++q) {
        float4 v = hr[q];
        atomicAdd(ac + q * 4 + 0, v.x * nrm);
        atomicAdd(ac + q * 4 + 1, v.y * nrm);
        atomicAdd(ac + q * 4 + 2, v.z * nrm);
        atomicAdd(ac + q * 4 + 3, v.w * nrm);
    }
}

__global__ __launch_bounds__(TPB) void relu_gemm2_kernel(const float* __restrict__ acc1,
                                                         const float* __restrict__ h1lin,
                                                         const float* __restrict__ dinv,
                                                         const float* __restrict__ b1,
                                                         const float* __restrict__ W2,
                                                         const float* __restrict__ b2,
                                                         float* __restrict__ h,
                                                         float* __restrict__ h2,
                                                         float* __restrict__ node_out, int N) {
    int i = blockIdx.x * TPB + threadIdx.x;
    if (i >= N) return;
    float di = dinv[i];
    float sl = di * di;
    const float4* a1 = (const float4*)(acc1 + (size_t)i * 16);
    const float4* hl = (const float4*)(h1lin + (size_t)i * 16);
    float hv[16];
    #pragma unroll
    for (int q = 0; q < 4; ++q) {
        float4 av = a1[q], lv = hl[q];
        float v0 = av.x + lv.x * sl + b1[q * 4 + 0];
        float v1 = av.y + lv.y * sl + b1[q * 4 + 1];
        float v2 = av.z + lv.z * sl + b1[q * 4 + 2];
        float v3 = av.w + lv.w * sl + b1[q * 4 + 3];
        hv[q * 4 + 0] = v0 > 0.f ? v0 : 0.f;
        hv[q * 4 + 1] = v1 > 0.f ? v1 : 0.f;
        hv[q * 4 + 2] = v2 > 0.f ? v2 : 0.f;
        hv[q * 4 + 3] = v3 > 0.f ? v3 : 0.f;
    }
    float4* ho = (float4*)(h + (size_t)i * 16);
    #pragma unroll
    for (int q = 0; q < 4; ++q) {
        float4 v = {hv[q * 4 + 0], hv[q * 4 + 1], hv[q * 4 + 2], hv[q * 4 + 3]};
        ho[q] = v;
    }
    float a = 0.f, b = 0.f;
    #pragma unroll
    for (int k = 0; k < 16; ++k) {
        a = fmaf(hv[k], W2[k * 2 + 0], a);
        b = fmaf(hv[k], W2[k * 2 + 1], b);
    }
    h2[(size_t)i * 2 + 0] = a;
    h2[(size_t)i * 2 + 1] = b;
    // init node_out with self-loop term + bias; edge_kernel atomics add the rest
    node_out[(size_t)i * 2 + 0] = a * sl + b2[0];
    node_out[(size_t)i * 2 + 1] = b * sl + b2[1];
}

__global__ __launch_bounds__(TPB) void edge_kernel(const int* __restrict__ ei,
                                                   const float* __restrict__ dinv,
                                                   const float* __restrict__ h,
                                                   const float* __restrict__ h2,
                                                   const float* __restrict__ We1,
                                                   const float* __restrict__ be1,
                                                   const float* __restrict__ We2,
                                                   const float* __restrict__ be2,
                                                   float* __restrict__ node_out,
                                                   float* __restrict__ edge_out, int E) {
    int e = blockIdx.x * TPB + threadIdx.x;
    if (e >= E) return;
    int r = ei[e], c = ei[(size_t)E + e];

    float ef[32];
    const float4* hr = (const float4*)(h + (size_t)r * 16);
    const float4* hc = (const float4*)(h + (size_t)c * 16);
    #pragma unroll
    for (int q = 0; q < 4; ++q) {
        float4 v = hr[q];
        ef[q * 4 + 0] = v.x; ef[q * 4 + 1] = v.y; ef[q * 4 + 2] = v.z; ef[q * 4 + 3] = v.w;
    }
    #pragma unroll
    for (int q = 0; q < 4; ++q) {
        float4 v = hc[q];
        ef[16 + q * 4 + 0] = v.x; ef[16 + q * 4 + 1] = v.y;
        ef[16 + q * 4 + 2] = v.z; ef[16 + q * 4 + 3] = v.w;
    }

    float acc[16];
    #pragma unroll
    for (int k = 0; k < 16; ++k) acc[k] = be1[k];
    // We1 accesses are wave-uniform -> scalar loads + v_fmac with SGPR operand.
    for (int j = 0; j < 32; ++j) {
        float xv = ef[j];
        #pragma unroll
        for (int k = 0; k < 16; ++k)
            acc[k] = fmaf(xv, We1[j * 16 + k], acc[k]);
    }
    float z = be2[0];
    #pragma unroll
    for (int k = 0; k < 16; ++k) {
        float ek = acc[k] > 0.f ? acc[k] : 0.f;
        z = fmaf(ek, We2[k], z);
    }
    edge_out[e] = 1.0f / (1.0f + expf(-z));

    float nrm = dinv[r] * dinv[c];
    atomicAdd(&node_out[(size_t)c * 2 + 0], h2[(size_t)r * 2 + 0] * nrm);
    atomicAdd(&node_out[(size_t)c * 2 + 1], h2[(size_t)r * 2 + 1] * nrm);
}

extern "C" void kernel_launch(void* const* d_in, const int* in_sizes, int n_in,
                              void* d_out, int out_size, void* d_ws, size_t ws_size,
                              hipStream_t stream) {
    const float* x   = (const float*)d_in[0];
    const int*   ei  = (const int*)d_in[1];   // int64 in reference, int32 on device
    const float* W1  = (const float*)d_in[2];
    const float* b1  = (const float*)d_in[3];
    const float* W2  = (const float*)d_in[4];
    const float* b2  = (const float*)d_in[5];
    const float* We1 = (const float*)d_in[6];
    const float* be1 = (const float*)d_in[7];
    const float* We2 = (const float*)d_in[8];
    const float* be2 = (const float*)d_in[9];

    int N = in_sizes[0] / 128;
    int E = in_sizes[1] / 2;

    float* ws    = (float*)d_ws;
    float* deg   = ws;                       // N floats (becomes dinv in place)
    float* h1lin = deg + (size_t)N;          // 16N
    float* acc1  = h1lin + (size_t)16 * N;   // 16N
    float* h     = acc1 + (size_t)16 * N;    // 16N
    float* h2    = h + (size_t)16 * N;       // 2N

    float* node_out = (float*)d_out;                 // [N,2] row-major
    float* edge_out = node_out + (size_t)2 * N;      // [E]

    int nbN = (N + TPB - 1) / TPB;
    int nbE = (E + TPB - 1) / TPB;
    int nbG = (N + 63) / 64;

    hipLaunchKernelGGL(init_kernel,      dim3(nbN), dim3(TPB), 0, stream, deg, acc1, N);
    hipLaunchKernelGGL(degree_kernel,    dim3(nbE), dim3(TPB), 0, stream, ei + (size_t)E, deg, E);
    hipLaunchKernelGGL(dinv_kernel,      dim3(nbN), dim3(TPB), 0, stream, deg, N);
    hipLaunchKernelGGL(gemm1_kernel,     dim3(nbG), dim3(TPB), 0, stream, x, W1, h1lin, N);
    hipLaunchKernelGGL(agg1_kernel,      dim3(nbE), dim3(TPB), 0, stream, ei, deg, h1lin, acc1, E);
    hipLaunchKernelGGL(relu_gemm2_kernel,dim3(nbN), dim3(TPB), 0, stream, acc1, h1lin, deg, b1, W2, b2, h, h2, node_out, N);
    hipLaunchKernelGGL(edge_kernel,      dim3(nbE), dim3(TPB), 0, stream, ei, deg, h, h2, We1, be1, We2, be2, node_out, edge_out, E);
}

// Round 3
// 664.449 us; speedup vs baseline: 4.7575x; 4.7575x over previous
//
#include <hip/hip_runtime.h>
#include <math.h>

// SimpleGNN forward on MI355X — CSR gather version (no f32 scatter atomics).
//
// Stages:
//   zero    : count = 0
//   count   : count[col]++ per edge (int atomics)
//   scanA/B/C: exclusive prefix scan of count -> rowptr; cursor=rowptr (in count array);
//             dinv[i] = rsqrt(count[i]+1)
//   scatter : csr_src[cursor[col]++] = row  (int atomics)
//   gemm1   : h1lin = x @ W1                       [N,16]
//   gather1 : per node c (16 lanes): acc = sum_{in-edges} h1lin[src]*dinv[src];
//             h = relu((acc + h1lin[c]*dinv[c])*dinv[c] + b1);
//             h2 = h @ W2;  node_out = h2*dinv^2 + b2
//   edgemlp : edge_out = sigmoid(relu([h[r],h[c]]@We1+be1)@We2+be2)
//   gather2 : node_out[c] += dinv[c] * sum_{in-edges} h2[src]*dinv[src]
//
// Workspace: ints count[N] rowptr[N+1] partials[256] csr_src[E];
//            floats dinv[N] h1lin[16N] h[16N] h2[2N]   (~28 MB total)

#define TPB 256

__global__ __launch_bounds__(TPB) void zero_count_kernel(int* __restrict__ count, int N) {
    int i = blockIdx.x * TPB + threadIdx.x;
    if (i < N) count[i] = 0;
}

__global__ __launch_bounds__(TPB) void count_kernel(const int* __restrict__ col,
                                                    int* __restrict__ count, int E) {
    int e = blockIdx.x * TPB + threadIdx.x;
    if (e < E) atomicAdd(&count[col[e]], 1);
}

// partials[b] = sum of count[b*1024 .. b*1024+1023]
__global__ __launch_bounds__(TPB) void scanA_kernel(const int* __restrict__ count,
                                                    int* __restrict__ partials, int N) {
    __shared__ int s[TPB];
    int t = threadIdx.x;
    int base = blockIdx.x * 1024 + t * 4;
    int sum = 0;
    #pragma unroll
    for (int k = 0; k < 4; ++k) {
        int i = base + k;
        if (i < N) sum += count[i];
    }
    s[t] = sum; __syncthreads();
    for (int off = 128; off > 0; off >>= 1) {
        if (t < off) s[t] += s[t + off];
        __syncthreads();
    }
    if (t == 0) partials[blockIdx.x] = s[0];
}

// serial exclusive scan of partials; rowptr[N] = total
__global__ void scanB_kernel(int* __restrict__ partials, int* __restrict__ rowptr,
                             int nb, int N) {
    if (threadIdx.x == 0 && blockIdx.x == 0) {
        int run = 0;
        for (int b = 0; b < nb; ++b) { int t = partials[b]; partials[b] = run; run += t; }
        rowptr[N] = run;
    }
}

// per-chunk exclusive scan: rowptr[i]; cursor (reuses count array); dinv
__global__ __launch_bounds__(TPB) void scanC_kernel(int* __restrict__ countcur,
                                                    const int* __restrict__ partials,
                                                    int* __restrict__ rowptr,
                                                    float* __restrict__ dinv, int N) {
    __shared__ int s[TPB];
    int t = threadIdx.x;
    int idx = blockIdx.x * 1024 + t * 4;
    int c0 = 0, c1 = 0, c2 = 0, c3 = 0;
    if (idx     < N) c0 = countcur[idx];
    if (idx + 1 < N) c1 = countcur[idx + 1];
    if (idx + 2 < N) c2 = countcur[idx + 2];
    if (idx + 3 < N) c3 = countcur[idx + 3];
    int ts = c0 + c1 + c2 + c3;
    s[t] = ts; __syncthreads();
    // inclusive Hillis-Steele over thread sums
    for (int off = 1; off < TPB; off <<= 1) {
        int v = (t >= off) ? s[t - off] : 0;
        __syncthreads();
        s[t] += v;
        __syncthreads();
    }
    int ex = s[t] - ts + partials[blockIdx.x];
    int e0 = ex, e1 = ex + c0, e2 = e1 + c1, e3 = e2 + c2;
    if (idx < N) {
        rowptr[idx] = e0; countcur[idx] = e0;
        dinv[idx] = rsqrtf((float)c0 + 1.0f);
    }
    if (idx + 1 < N) {
        rowptr[idx + 1] = e1; countcur[idx + 1] = e1;
        dinv[idx + 1] = rsqrtf((float)c1 + 1.0f);
    }
    if (idx + 2 < N) {
        rowptr[idx + 2] = e2; countcur[idx + 2] = e2;
        dinv[idx + 2] = rsqrtf((float)c2 + 1.0f);
    }
    if (idx + 3 < N) {
        rowptr[idx + 3] = e3; countcur[idx + 3] = e3;
        dinv[idx + 3] = rsqrtf((float)c3 + 1.0f);
    }
}

__global__ __launch_bounds__(TPB) void scatter_kernel(const int* __restrict__ ei,
                                                      int* __restrict__ cursor,
                                                      int* __restrict__ csr_src, int E) {
    int e = blockIdx.x * TPB + threadIdx.x;
    if (e >= E) return;
    int r = ei[e], c = ei[(size_t)E + e];
    int pos = atomicAdd(&cursor[c], 1);
    csr_src[pos] = r;
}

// x [N,128] @ W1 [128,16] -> h1lin [N,16].  64 rows per block.
__global__ __launch_bounds__(TPB) void gemm1_kernel(const float* __restrict__ x,
                                                    const float* __restrict__ W1,
                                                    float* __restrict__ h1lin, int N) {
    __shared__ float xs[64][132];
    __shared__ float w1s[128 * 16];
    int r0 = blockIdx.x * 64;
    int t  = threadIdx.x;

    for (int l = t; l < 512; l += TPB)
        ((float4*)w1s)[l] = ((const float4*)W1)[l];
    for (int l = t; l < 2048; l += TPB) {
        int r = l >> 5, q = l & 31;
        float4 v = {0.f, 0.f, 0.f, 0.f};
        if (r0 + r < N) v = ((const float4*)(x + (size_t)(r0 + r) * 128))[q];
        *(float4*)&xs[r][q * 4] = v;
    }
    __syncthreads();

    int row = t >> 2, kq = t & 3;
    float4 a = {0.f, 0.f, 0.f, 0.f};
    #pragma unroll
    for (int j4 = 0; j4 < 32; ++j4) {
        float4 xv = *(const float4*)&xs[row][j4 * 4];
        const float* wp = &w1s[(j4 * 4) * 16 + kq * 4];
        float4 w0 = *(const float4*)(wp +  0);
        float4 w1 = *(const float4*)(wp + 16);
        float4 w2 = *(const float4*)(wp + 32);
        float4 w3 = *(const float4*)(wp + 48);
        a.x = fmaf(xv.x, w0.x, a.x); a.y = fmaf(xv.x, w0.y, a.y);
        a.z = fmaf(xv.x, w0.z, a.z); a.w = fmaf(xv.x, w0.w, a.w);
        a.x = fmaf(xv.y, w1.x, a.x); a.y = fmaf(xv.y, w1.y, a.y);
        a.z = fmaf(xv.y, w1.z, a.z); a.w = fmaf(xv.y, w1.w, a.w);
        a.x = fmaf(xv.z, w2.x, a.x); a.y = fmaf(xv.z, w2.y, a.y);
        a.z = fmaf(xv.z, w2.z, a.z); a.w = fmaf(xv.z, w2.w, a.w);
        a.x = fmaf(xv.w, w3.x, a.x); a.y = fmaf(xv.w, w3.y, a.y);
        a.z = fmaf(xv.w, w3.z, a.z); a.w = fmaf(xv.w, w3.w, a.w);
    }
    if (r0 + row < N)
        *(float4*)(h1lin + (size_t)(r0 + row) * 16 + kq * 4) = a;
}

// 16 lanes per node; 4 nodes per wave; 16 nodes per block.
__global__ __launch_bounds__(TPB) void gather1_kernel(const int* __restrict__ rowptr,
                                                      const int* __restrict__ csr_src,
                                                      const float* __restrict__ dinv,
                                                      const float* __restrict__ h1lin,
                                                      const float* __restrict__ b1,
                                                      const float* __restrict__ W2,
                                                      const float* __restrict__ b2,
                                                      float* __restrict__ h,
                                                      float* __restrict__ h2,
                                                      float* __restrict__ node_out, int N) {
    int t = threadIdx.x, g = t & 15;
    int c = blockIdx.x * 16 + (t >> 4);
    if (c >= N) return;  // N % 16 == 0 for this problem; guard never diverges a wave
    int start = rowptr[c], end = rowptr[c + 1];
    float acc = 0.f;
    for (int j0 = start; j0 < end; j0 += 16) {
        int myj = j0 + g;
        int   msrc = (myj < end) ? csr_src[myj] : 0;
        float mdi  = (myj < end) ? dinv[msrc]   : 0.f;
        int cnt = end - j0; if (cnt > 16) cnt = 16;
        if (cnt == 16) {
            #pragma unroll
            for (int jj = 0; jj < 16; ++jj) {
                int   src = __shfl(msrc, jj, 16);
                float ds  = __shfl(mdi,  jj, 16);
                acc = fmaf(h1lin[(size_t)src * 16 + g], ds, acc);
            }
        } else {
            for (int jj = 0; jj < cnt; ++jj) {
                int   src = __shfl(msrc, jj, 16);
                float ds  = __shfl(mdi,  jj, 16);
                acc = fmaf(h1lin[(size_t)src * 16 + g], ds, acc);
            }
        }
    }
    float di = dinv[c];
    float pre = fmaf(fmaf(h1lin[(size_t)c * 16 + g], di, acc), di, b1[g]);
    float hv = pre > 0.f ? pre : 0.f;
    h[(size_t)c * 16 + g] = hv;
    float a = hv * W2[g * 2 + 0];
    float b = hv * W2[g * 2 + 1];
    #pragma unroll
    for (int off = 8; off > 0; off >>= 1) {
        a += __shfl_xor(a, off, 16);
        b += __shfl_xor(b, off, 16);
    }
    if (g == 0) {
        float sl = di * di;
        h2[(size_t)c * 2 + 0] = a;
        h2[(size_t)c * 2 + 1] = b;
        node_out[(size_t)c * 2 + 0] = fmaf(a, sl, b2[0]);
        node_out[(size_t)c * 2 + 1] = fmaf(b, sl, b2[1]);
    }
}

__global__ __launch_bounds__(TPB) void edge_mlp_kernel(const int* __restrict__ ei,
                                                       const float* __restrict__ h,
                                                       const float* __restrict__ We1,
                                                       const float* __restrict__ be1,
                                                       const float* __restrict__ We2,
                                                       const float* __restrict__ be2,
                                                       float* __restrict__ edge_out, int E) {
    int e = blockIdx.x * TPB + threadIdx.x;
    if (e >= E) return;
    int r = ei[e], c = ei[(size_t)E + e];

    float ef[32];
    const float4* hr = (const float4*)(h + (size_t)r * 16);
    const float4* hc = (const float4*)(h + (size_t)c * 16);
    #pragma unroll
    for (int q = 0; q < 4; ++q) {
        float4 v = hr[q];
        ef[q * 4 + 0] = v.x; ef[q * 4 + 1] = v.y; ef[q * 4 + 2] = v.z; ef[q * 4 + 3] = v.w;
    }
    #pragma unroll
    for (int q = 0; q < 4; ++q) {
        float4 v = hc[q];
        ef[16 + q * 4 + 0] = v.x; ef[16 + q * 4 + 1] = v.y;
        ef[16 + q * 4 + 2] = v.z; ef[16 + q * 4 + 3] = v.w;
    }

    float acc[16];
    #pragma unroll
    for (int k = 0; k < 16; ++k) acc[k] = be1[k];
    for (int j = 0; j < 32; ++j) {
        float xv = ef[j];
        #pragma unroll
        for (int k = 0; k < 16; ++k)
            acc[k] = fmaf(xv, We1[j * 16 + k], acc[k]);
    }
    float z = be2[0];
    #pragma unroll
    for (int k = 0; k < 16; ++k) {
        float ek = acc[k] > 0.f ? acc[k] : 0.f;
        z = fmaf(ek, We2[k], z);
    }
    edge_out[e] = 1.0f / (1.0f + expf(-z));
}

__global__ __launch_bounds__(TPB) void gather2_kernel(const int* __restrict__ rowptr,
                                                      const int* __restrict__ csr_src,
                                                      const float* __restrict__ dinv,
                                                      const float* __restrict__ h2,
                                                      float* __restrict__ node_out, int N) {
    int c = blockIdx.x * TPB + threadIdx.x;
    if (c >= N) return;
    int start = rowptr[c], end = rowptr[c + 1];
    float a = 0.f, b = 0.f;
    for (int j = start; j < end; ++j) {
        int src = csr_src[j];
        float ds = dinv[src];
        float2 hv = *(const float2*)(h2 + (size_t)src * 2);
        a = fmaf(hv.x, ds, a);
        b = fmaf(hv.y, ds, b);
    }
    float di = dinv[c];
    node_out[(size_t)c * 2 + 0] += a * di;
    node_out[(size_t)c * 2 + 1] += b * di;
}

extern "C" void kernel_launch(void* const* d_in, const int* in_sizes, int n_in,
                              void* d_out, int out_size, void* d_ws, size_t ws_size,
                              hipStream_t stream) {
    const float* x   = (const float*)d_in[0];
    const int*   ei  = (const int*)d_in[1];   // int64 in reference, int32 on device
    const float* W1  = (const float*)d_in[2];
    const float* b1  = (const float*)d_in[3];
    const float* W2  = (const float*)d_in[4];
    const float* b2  = (const float*)d_in[5];
    const float* We1 = (const float*)d_in[6];
    const float* be1 = (const float*)d_in[7];
    const float* We2 = (const float*)d_in[8];
    const float* be2 = (const float*)d_in[9];

    int N = in_sizes[0] / 128;
    int E = in_sizes[1] / 2;

    // workspace layout
    char* wsb = (char*)d_ws;
    int*   count    = (int*)wsb;                 wsb += (size_t)N * 4;        // becomes cursor
    int*   rowptr   = (int*)wsb;                 wsb += (size_t)(N + 1) * 4;
    int*   partials = (int*)wsb;                 wsb += 256 * 4;
    int*   csr_src  = (int*)wsb;                 wsb += (size_t)E * 4;
    float* dinv     = (float*)wsb;               wsb += (size_t)N * 4;
    float* h1lin    = (float*)wsb;               wsb += (size_t)N * 16 * 4;
    float* h        = (float*)wsb;               wsb += (size_t)N * 16 * 4;
    float* h2       = (float*)wsb;               wsb += (size_t)N * 2 * 4;

    float* node_out = (float*)d_out;                 // [N,2] row-major
    float* edge_out = node_out + (size_t)2 * N;      // [E]

    int nbN = (N + TPB - 1) / TPB;
    int nbE = (E + TPB - 1) / TPB;
    int nbG = (N + 63) / 64;
    int nbS = (N + 1023) / 1024;
    int nb16 = (N + 15) / 16;

    hipLaunchKernelGGL(zero_count_kernel, dim3(nbN), dim3(TPB), 0, stream, count, N);
    hipLaunchKernelGGL(count_kernel,      dim3(nbE), dim3(TPB), 0, stream, ei + (size_t)E, count, E);
    hipLaunchKernelGGL(scanA_kernel,      dim3(nbS), dim3(TPB), 0, stream, count, partials, N);
    hipLaunchKernelGGL(scanB_kernel,      dim3(1),   dim3(64),  0, stream, partials, rowptr, nbS, N);
    hipLaunchKernelGGL(scanC_kernel,      dim3(nbS), dim3(TPB), 0, stream, count, partials, rowptr, dinv, N);
    hipLaunchKernelGGL(scatter_kernel,    dim3(nbE), dim3(TPB), 0, stream, ei, count, csr_src, E);
    hipLaunchKernelGGL(gemm1_kernel,      dim3(nbG), dim3(TPB), 0, stream, x, W1, h1lin, N);
    hipLaunchKernelGGL(gather1_kernel,    dim3(nb16),dim3(TPB), 0, stream, rowptr, csr_src, dinv, h1lin, b1, W2, b2, h, h2, node_out, N);
    hipLaunchKernelGGL(edge_mlp_kernel,   dim3(nbE), dim3(TPB), 0, stream, ei, h, We1, be1, We2, be2, edge_out, E);
    hipLaunchKernelGGL(gather2_kernel,    dim3(nbN), dim3(TPB), 0, stream, rowptr, csr_src, dinv, h2, node_out, N);
}